// Round 3
// baseline (442.062 us; speedup 1.0000x reference)
//
#include <hip/hip_runtime.h>

// Problem: B=2048, C=16, S=2000, fp32.
// Reference collapses: softmax rows sum to 1 over m, so
// einsum('bcs,bcm->bcs', x, score) == x exactly. The kernel is therefore
// out = LN_c(Wp @ x[b,:,s] + bp) * gp + hp, a pure streaming op:
// 262 MB in + 262 MB out -> ~83 us roofline @ 6.3 TB/s achievable.
//
// R3 theory: occupancy is NOT the limiter (fills hit 6.5 TB/s at 10% occ,
// 8 VGPR; our R2 8-wave push was neutral). The limiter is access
// granularity: the 6.3 TB/s copy ubench and the fills use dwordx4
// (16 B/lane, 1 KB/wave/instr); our float2 kernel issues 2x the VMEM
// instructions at half the payload. R0 proved float4 works (132 us) but
// was register-strangled (~160 VGPR, all 16 loads live, ~3 waves/SIMD).
// R3 = float4 width + split-half loading (only 8 xv regs live, peak live
// ~116 VGPR) + __launch_bounds__(256,4) (VGPR<=128, no spill, 4 waves/SIMD).

#define NC 16          // channels
#define NS 2000        // sequence
#define SV (NS / 4)    // 500 float4 per (b,c) row
#define EPS 1e-5f
#define BLK 256

typedef float f32x4 __attribute__((ext_vector_type(4)));

__global__ __launch_bounds__(BLK, 4) void chanattn_fused(
    const float* __restrict__ x,
    const float* __restrict__ Wp,
    const float* __restrict__ bp,
    const float* __restrict__ gp,
    const float* __restrict__ hp,
    float* __restrict__ out,
    unsigned total)        // B * SV
{
    // Params in LDS, W transposed: sW4[cp][c/4] = Wp[c..c+3][cp], c contiguous
    // so one f32x4 read grabs 4 output channels for one input channel. All
    // lanes read the same address -> LDS broadcast, conflict-free.
    __shared__ f32x4 sW4[NC * NC / 4];
    __shared__ float sb[NC], sg[NC], sh[NC];
    const int tid = threadIdx.x;
    if (tid < NC * NC) ((float*)sW4)[(tid & (NC - 1)) * NC + (tid >> 4)] = Wp[tid];
    if (tid < NC) { sb[tid] = bp[tid]; sg[tid] = gp[tid]; sh[tid] = hp[tid]; }
    __syncthreads();

    const unsigned t = blockIdx.x * BLK + tid;
    if (t >= total) return;
    const unsigned b  = t / SV;        // const-division -> magic mul
    const unsigned s4 = t - b * SV;

    const f32x4* __restrict__ px = (const f32x4*)x   + (size_t)b * (NC * SV) + s4;
    f32x4*       __restrict__ po = (f32x4*)out       + (size_t)b * (NC * SV) + s4;

    // y[c] = bp[c] + sum_cp Wp[c][cp] * x[cp]   (4 positions at once)
    f32x4 y[NC];
#pragma unroll
    for (int c = 0; c < NC; ++c) {
        const float bb = sb[c];
        y[c].x = bb; y[c].y = bb; y[c].z = bb; y[c].w = bb;
    }

    // ---- first 8 input channels: 8 dwordx4 loads in flight, then FMA ----
    f32x4 xv[8];
#pragma unroll
    for (int cp = 0; cp < 8; ++cp)
        xv[cp] = __builtin_nontemporal_load(&px[cp * SV]);
#pragma unroll
    for (int cp = 0; cp < 8; ++cp) {
        const f32x4 xc = xv[cp];
#pragma unroll
        for (int k = 0; k < 4; ++k) {
            const f32x4 w = sW4[cp * 4 + k];
            y[4 * k + 0].x = fmaf(w.x, xc.x, y[4 * k + 0].x);
            y[4 * k + 0].y = fmaf(w.x, xc.y, y[4 * k + 0].y);
            y[4 * k + 0].z = fmaf(w.x, xc.z, y[4 * k + 0].z);
            y[4 * k + 0].w = fmaf(w.x, xc.w, y[4 * k + 0].w);
            y[4 * k + 1].x = fmaf(w.y, xc.x, y[4 * k + 1].x);
            y[4 * k + 1].y = fmaf(w.y, xc.y, y[4 * k + 1].y);
            y[4 * k + 1].z = fmaf(w.y, xc.z, y[4 * k + 1].z);
            y[4 * k + 1].w = fmaf(w.y, xc.w, y[4 * k + 1].w);
            y[4 * k + 2].x = fmaf(w.z, xc.x, y[4 * k + 2].x);
            y[4 * k + 2].y = fmaf(w.z, xc.y, y[4 * k + 2].y);
            y[4 * k + 2].z = fmaf(w.z, xc.z, y[4 * k + 2].z);
            y[4 * k + 2].w = fmaf(w.z, xc.w, y[4 * k + 2].w);
            y[4 * k + 3].x = fmaf(w.w, xc.x, y[4 * k + 3].x);
            y[4 * k + 3].y = fmaf(w.w, xc.y, y[4 * k + 3].y);
            y[4 * k + 3].z = fmaf(w.w, xc.z, y[4 * k + 3].z);
            y[4 * k + 3].w = fmaf(w.w, xc.w, y[4 * k + 3].w);
        }
    }

    // ---- second 8 input channels: reuse xv regs (loads overlap FMAs) ----
#pragma unroll
    for (int cp = 8; cp < NC; ++cp)
        xv[cp - 8] = __builtin_nontemporal_load(&px[cp * SV]);
#pragma unroll
    for (int cp = 8; cp < NC; ++cp) {
        const f32x4 xc = xv[cp - 8];
#pragma unroll
        for (int k = 0; k < 4; ++k) {
            const f32x4 w = sW4[cp * 4 + k];
            y[4 * k + 0].x = fmaf(w.x, xc.x, y[4 * k + 0].x);
            y[4 * k + 0].y = fmaf(w.x, xc.y, y[4 * k + 0].y);
            y[4 * k + 0].z = fmaf(w.x, xc.z, y[4 * k + 0].z);
            y[4 * k + 0].w = fmaf(w.x, xc.w, y[4 * k + 0].w);
            y[4 * k + 1].x = fmaf(w.y, xc.x, y[4 * k + 1].x);
            y[4 * k + 1].y = fmaf(w.y, xc.y, y[4 * k + 1].y);
            y[4 * k + 1].z = fmaf(w.y, xc.z, y[4 * k + 1].z);
            y[4 * k + 1].w = fmaf(w.y, xc.w, y[4 * k + 1].w);
            y[4 * k + 2].x = fmaf(w.z, xc.x, y[4 * k + 2].x);
            y[4 * k + 2].y = fmaf(w.z, xc.y, y[4 * k + 2].y);
            y[4 * k + 2].z = fmaf(w.z, xc.z, y[4 * k + 2].z);
            y[4 * k + 2].w = fmaf(w.z, xc.w, y[4 * k + 2].w);
            y[4 * k + 3].x = fmaf(w.w, xc.x, y[4 * k + 3].x);
            y[4 * k + 3].y = fmaf(w.w, xc.y, y[4 * k + 3].y);
            y[4 * k + 3].z = fmaf(w.w, xc.z, y[4 * k + 3].z);
            y[4 * k + 3].w = fmaf(w.w, xc.w, y[4 * k + 3].w);
        }
    }

    // LayerNorm over the 16 channels, per position (two-pass, in registers).
    f32x4 sum; sum.x = sum.y = sum.z = sum.w = 0.f;
#pragma unroll
    for (int c = 0; c < NC; ++c) {
        sum.x += y[c].x; sum.y += y[c].y; sum.z += y[c].z; sum.w += y[c].w;
    }
    const float inv = 1.0f / NC;
    const float mux = sum.x * inv, muy = sum.y * inv,
                muz = sum.z * inv, muw = sum.w * inv;

    f32x4 var; var.x = var.y = var.z = var.w = 0.f;
#pragma unroll
    for (int c = 0; c < NC; ++c) {
        const float dx = y[c].x - mux, dy = y[c].y - muy,
                    dz = y[c].z - muz, dw = y[c].w - muw;
        var.x = fmaf(dx, dx, var.x);
        var.y = fmaf(dy, dy, var.y);
        var.z = fmaf(dz, dz, var.z);
        var.w = fmaf(dw, dw, var.w);
    }
    const float rx = rsqrtf(var.x * inv + EPS);
    const float ry = rsqrtf(var.y * inv + EPS);
    const float rz = rsqrtf(var.z * inv + EPS);
    const float rw = rsqrtf(var.w * inv + EPS);

#pragma unroll
    for (int c = 0; c < NC; ++c) {
        const float g = sg[c], h = sh[c];
        f32x4 o;
        o.x = fmaf((y[c].x - mux) * rx, g, h);
        o.y = fmaf((y[c].y - muy) * ry, g, h);
        o.z = fmaf((y[c].z - muz) * rz, g, h);
        o.w = fmaf((y[c].w - muw) * rw, g, h);
        __builtin_nontemporal_store(o, &po[c * SV]);
    }
}

extern "C" void kernel_launch(void* const* d_in, const int* in_sizes, int n_in,
                              void* d_out, int out_size, void* d_ws, size_t ws_size,
                              hipStream_t stream) {
    // setup_inputs order: x, Wq, bq, gq, hq, Wk, bk, gk, hk, Wp, bp, gp, hp
    const float* x  = (const float*)d_in[0];
    const float* Wp = (const float*)d_in[9];
    const float* bp = (const float*)d_in[10];
    const float* gp = (const float*)d_in[11];
    const float* hp = (const float*)d_in[12];
    float* out = (float*)d_out;

    const unsigned B = (unsigned)(in_sizes[0] / (NC * NS));  // 2048
    const unsigned total = B * SV;                            // 1,024,000
    const unsigned grid = (total + BLK - 1) / BLK;            // 4000
    chanattn_fused<<<grid, BLK, 0, stream>>>(x, Wp, bp, gp, hp, out, total);
}

// Round 4
// 434.882 us; speedup vs baseline: 1.0165x; 1.0165x over previous
//
#include <hip/hip_runtime.h>

// Problem: B=2048, C=16, S=2000, fp32.
// Reference collapses: softmax rows sum to 1 over m, so
// einsum('bcs,bcm->bcs', x, score) == x exactly. The kernel is therefore
// out = LN_c(Wp @ x[b,:,s] + bp) * gp + hp, a pure streaming op:
// 262 MB in + 262 MB out -> ~83 us roofline @ 6.3 TB/s achievable.
//
// Session ledger (timed region = 2 harness poison-fills ~320us + kernel):
//   R1 float2 (256,4) all-16 loads:  435.5 total (~111 us kernel)  <- best
//   R2 float2 (256,8) split loads:   437.3 (~117)   occupancy: falsified
//   R3 float4 (256,4) split loads:   442.1 (~120)   granularity: falsified
// Deltas are at the fill-noise floor (+-8us). R4 = revert to the measured
// best (R1 structure) + two riskless cuts:
//   1. f32x4 weight broadcasts (64 ds_read_b128, kept from R2/R3).
//   2. Centered weights: mean_c(Wx+b) is affine in x, so pre-subtracting
//      the column-mean from W and b makes the LN mean identically 0 --
//      deletes the whole mean pass and every (y-mu) subtraction.

#define NC 16          // channels
#define NS 2000        // sequence
#define SV2 (NS / 2)   // 1000 float2 per (b,c) row
#define EPS 1e-5f
#define BLK 256

typedef float f32x2 __attribute__((ext_vector_type(2)));
typedef float f32x4 __attribute__((ext_vector_type(4)));

__global__ __launch_bounds__(BLK, 4) void chanattn_fused(
    const float* __restrict__ x,
    const float* __restrict__ Wp,
    const float* __restrict__ bp,
    const float* __restrict__ gp,
    const float* __restrict__ hp,
    float* __restrict__ out,
    unsigned total)        // B * SV2
{
    // sW[cp][c] = Wp[c][cp] (transposed; c contiguous so one f32x4 read
    // grabs 4 output channels). Then center: sW[cp][c] -= mean_c(sW[cp][:]),
    // sbc[c] = b[c] - mean(b). All main-loop reads are same-address -> LDS
    // broadcast, conflict-free.
    __shared__ __align__(16) float sW[NC * NC];
    __shared__ float sm[NC];                  // per-cp column mean of W^T
    __shared__ float sb[NC], sbc[NC], sg[NC], sh[NC];
    const int tid = threadIdx.x;
    if (tid < NC * NC) sW[(tid & (NC - 1)) * NC + (tid >> 4)] = Wp[tid];
    if (tid < NC) { sb[tid] = bp[tid]; sg[tid] = gp[tid]; sh[tid] = hp[tid]; }
    __syncthreads();
    if (tid < NC) {
        float s = 0.f;
#pragma unroll
        for (int j = 0; j < NC; ++j) s += sW[tid * NC + j];
        sm[tid] = s * (1.0f / NC);
    }
    __syncthreads();
    if (tid < NC * NC) sW[tid] -= sm[tid >> 4];
    if (tid < NC) {
        float mb = 0.f;
#pragma unroll
        for (int j = 0; j < NC; ++j) mb += sb[j];
        sbc[tid] = sb[tid] - mb * (1.0f / NC);   // write to sbc: no race
    }
    __syncthreads();
    const f32x4* __restrict__ sW4 = (const f32x4*)sW;

    const unsigned t = blockIdx.x * BLK + tid;
    if (t >= total) return;
    const unsigned b  = t / SV2;       // const-division -> magic mul
    const unsigned s2 = t - b * SV2;

    const f32x2* __restrict__ px = (const f32x2*)x   + (size_t)b * (NC * SV2) + s2;
    f32x2*       __restrict__ po = (f32x2*)out       + (size_t)b * (NC * SV2) + s2;

    // 16 independent nontemporal loads in flight per wave (512B each,
    // perfectly coalesced). This exact shape measured best (R1).
    f32x2 xv[NC];
#pragma unroll
    for (int c = 0; c < NC; ++c)
        xv[c] = __builtin_nontemporal_load(&px[c * SV2]);

    // y[c] = bc[c] + sum_cp Wc[c][cp] * x[cp]  -- centered, so mean(y) == 0.
    f32x2 y[NC];
#pragma unroll
    for (int c = 0; c < NC; ++c) {
        const float bb = sbc[c];
        y[c].x = bb; y[c].y = bb;
    }
#pragma unroll
    for (int cp = 0; cp < NC; ++cp) {
        const f32x2 xc = xv[cp];
#pragma unroll
        for (int k = 0; k < 4; ++k) {
            const f32x4 w = sW4[cp * 4 + k];
            y[4 * k + 0].x = fmaf(w.x, xc.x, y[4 * k + 0].x);
            y[4 * k + 0].y = fmaf(w.x, xc.y, y[4 * k + 0].y);
            y[4 * k + 1].x = fmaf(w.y, xc.x, y[4 * k + 1].x);
            y[4 * k + 1].y = fmaf(w.y, xc.y, y[4 * k + 1].y);
            y[4 * k + 2].x = fmaf(w.z, xc.x, y[4 * k + 2].x);
            y[4 * k + 2].y = fmaf(w.z, xc.y, y[4 * k + 2].y);
            y[4 * k + 3].x = fmaf(w.w, xc.x, y[4 * k + 3].x);
            y[4 * k + 3].y = fmaf(w.w, xc.y, y[4 * k + 3].y);
        }
    }

    // LayerNorm with mu == 0: var = mean(y^2), out = y*rsqrt(var+eps)*g + h.
    float vx = 0.f, vy = 0.f;
#pragma unroll
    for (int c = 0; c < NC; ++c) {
        vx = fmaf(y[c].x, y[c].x, vx);
        vy = fmaf(y[c].y, y[c].y, vy);
    }
    const float inv = 1.0f / NC;
    const float rx = rsqrtf(vx * inv + EPS);
    const float ry = rsqrtf(vy * inv + EPS);

#pragma unroll
    for (int c = 0; c < NC; ++c) {
        const float g = sg[c], h = sh[c];
        f32x2 o;
        o.x = fmaf(y[c].x * rx, g, h);
        o.y = fmaf(y[c].y * ry, g, h);
        __builtin_nontemporal_store(o, &po[c * SV2]);
    }
}

extern "C" void kernel_launch(void* const* d_in, const int* in_sizes, int n_in,
                              void* d_out, int out_size, void* d_ws, size_t ws_size,
                              hipStream_t stream) {
    // setup_inputs order: x, Wq, bq, gq, hq, Wk, bk, gk, hk, Wp, bp, gp, hp
    const float* x  = (const float*)d_in[0];
    const float* Wp = (const float*)d_in[9];
    const float* bp = (const float*)d_in[10];
    const float* gp = (const float*)d_in[11];
    const float* hp = (const float*)d_in[12];
    float* out = (float*)d_out;

    const unsigned B = (unsigned)(in_sizes[0] / (NC * NS));  // 2048
    const unsigned total = B * SV2;                           // 2,048,000
    const unsigned grid = (total + BLK - 1) / BLK;            // 8000
    chanattn_fused<<<grid, BLK, 0, stream>>>(x, Wp, bp, gp, hp, out, total);
}